// Round 6
// baseline (8852.654 us; speedup 1.0000x reference)
//
#include <hip/hip_runtime.h>
#include <hip/hip_bf16.h>
#include <math.h>

// ---- problem constants ----
#define NL 26
#define TT 16
#define DD 768
#define HDD 128
#define FFF 3072
#define VV 32000
#define SCCH 4096
#define STOT 4112      // SC + T
#define OQKV 1536      // NG*(G+2)*HD
#define EPSF 1e-6f
#define SCALEQ 0.08838834764831845f  // 1/sqrt(128)

// ---------- helpers ----------
__device__ __forceinline__ float d4(const float4 a, const float4 b) {
    return fmaf(a.x, b.x, fmaf(a.y, b.y, fmaf(a.z, b.z, a.w * b.w)));
}
__device__ __forceinline__ float4 fma4(float p, const float4 v, float4 a) {
    return make_float4(fmaf(p, v.x, a.x), fmaf(p, v.y, a.y),
                       fmaf(p, v.z, a.z), fmaf(p, v.w, a.w));
}
__device__ __forceinline__ float4 f4add4(float4 a, float4 b, float4 c, float4 d) {
    return make_float4((a.x + b.x) + (c.x + d.x), (a.y + b.y) + (c.y + d.y),
                       (a.z + b.z) + (c.z + d.z), (a.w + b.w) + (c.w + d.w));
}
// h + f*s*(1+w)
__device__ __forceinline__ float4 f4res(float4 h, float4 f, float s, float4 w) {
    return make_float4(fmaf(f.x * s, 1.f + w.x, h.x), fmaf(f.y * s, 1.f + w.y, h.y),
                       fmaf(f.z * s, 1.f + w.z, h.z), fmaf(f.w * s, 1.f + w.w, h.w));
}
// h*s*(1+w)
__device__ __forceinline__ float4 f4nrm(float4 h, float s, float4 w) {
    return make_float4(h.x * s * (1.f + w.x), h.y * s * (1.f + w.y),
                       h.z * s * (1.f + w.z), h.w * s * (1.f + w.w));
}
__device__ __forceinline__ float r16(float v) {
    v += __shfl_xor(v, 1); v += __shfl_xor(v, 2); v += __shfl_xor(v, 4); v += __shfl_xor(v, 8);
    return v;
}
__device__ __forceinline__ float r8(float v) {
    v += __shfl_xor(v, 1); v += __shfl_xor(v, 2); v += __shfl_xor(v, 4);
    return v;
}
__device__ __forceinline__ float rwave(float v) {
    v += __shfl_xor(v, 32); v += __shfl_xor(v, 16); v += __shfl_xor(v, 8);
    v += __shfl_xor(v, 4);  v += __shfl_xor(v, 2);  v += __shfl_xor(v, 1);
    return v;
}

// GEMV inner: one weight row (K4 float4s) vs 16 token vectors (LDS or global).
template <int K4>
__device__ __forceinline__ void gemv_row(const float4* __restrict__ w4,
                                         const float* __restrict__ xs, int lane,
                                         float* __restrict__ acc) {
#pragma unroll
    for (int t = 0; t < TT; t++) acc[t] = 0.f;
    const float4* x4 = reinterpret_cast<const float4*>(xs);
#pragma unroll
    for (int it = 0; it < K4 / 64; ++it) {
        float4 w = w4[it * 64 + lane];
#pragma unroll
        for (int t = 0; t < TT; t++) {
            float4 x = x4[t * K4 + it * 64 + lane];
            acc[t] = fmaf(w.x, x.x, fmaf(w.y, x.y, fmaf(w.z, x.z, fmaf(w.w, x.w, acc[t]))));
        }
    }
#pragma unroll
    for (int t = 0; t < TT; t++) acc[t] = rwave(acc[t]);
}

// ---------- K1: (deferred ff residual) + pre-attn rmsnorm + QKV GEMV ----------
__global__ __launch_bounds__(256) void k_qkv(const int first,
                                             const float* __restrict__ hB,
                                             const float* __restrict__ ff,   // [4][16][768]
                                             const float* __restrict__ emb,
                                             const float* __restrict__ pofn_prev,
                                             const float* __restrict__ pan,
                                             const float* __restrict__ W,    // [1536][768]
                                             float* __restrict__ qkvo,       // [16][1536]
                                             float* __restrict__ hA) {
    __shared__ __align__(16) float xs[TT * DD];
    const int tid = threadIdx.x;
    const int row = tid >> 4, c16 = tid & 15;
    float4* xr = reinterpret_cast<float4*>(xs) + row * 192;
    float4* hA4 = reinterpret_cast<float4*>(hA) + row * 192;
    if (first) {
        const float4* e4 = reinterpret_cast<const float4*>(emb) + row * 192;
        float ss = 0.f;
#pragma unroll
        for (int k = 0; k < 12; k++) { int i = c16 + 16 * k; float4 v = e4[i]; xr[i] = v; ss += d4(v, v); }
        ss = r16(ss);
        float inv = rsqrtf(ss * (1.f / 768.f) + EPSF);
        if (blockIdx.x == 0) {
#pragma unroll
            for (int k = 0; k < 12; k++) { int i = c16 + 16 * k; hA4[i] = xr[i]; }
        }
        const float4* p4 = reinterpret_cast<const float4*>(pan);
#pragma unroll
        for (int k = 0; k < 12; k++) { int i = c16 + 16 * k; xr[i] = f4nrm(xr[i], inv, p4[i]); }
    } else {
        const float4* f0 = reinterpret_cast<const float4*>(ff) + row * 192;
        const float4* f1 = f0 + TT * 192;
        const float4* f2 = f1 + TT * 192;
        const float4* f3 = f2 + TT * 192;
        float ss = 0.f;
#pragma unroll
        for (int k = 0; k < 12; k++) {
            int i = c16 + 16 * k;
            float4 v = f4add4(f0[i], f1[i], f2[i], f3[i]);
            xr[i] = v; ss += d4(v, v);
        }
        ss = r16(ss);
        float inv = rsqrtf(ss * (1.f / 768.f) + EPSF);
        const float4* hb4 = reinterpret_cast<const float4*>(hB) + row * 192;
        const float4* po4 = reinterpret_cast<const float4*>(pofn_prev);
        float ss2 = 0.f;
#pragma unroll
        for (int k = 0; k < 12; k++) {
            int i = c16 + 16 * k;
            float4 v = f4res(hb4[i], xr[i], inv, po4[i]);
            xr[i] = v; ss2 += d4(v, v);
            if (blockIdx.x == 0) hA4[i] = v;
        }
        ss2 = r16(ss2);
        float inv2 = rsqrtf(ss2 * (1.f / 768.f) + EPSF);
        const float4* p4 = reinterpret_cast<const float4*>(pan);
#pragma unroll
        for (int k = 0; k < 12; k++) { int i = c16 + 16 * k; xr[i] = f4nrm(xr[i], inv2, p4[i]); }
    }
    __syncthreads();
    const int wv = tid >> 6, lane = tid & 63;
#pragma unroll
    for (int rr = 0; rr < 2; ++rr) {
        const int o = blockIdx.x * 8 + rr * 4 + wv;
        float acc[TT];
        gemv_row<192>(reinterpret_cast<const float4*>(W + (size_t)o * DD), xs, lane, acc);
        if (lane < TT) qkvo[lane * OQKV + o] = acc[lane];
    }
}

// ---------- K2: attention partials (flash-style over 64-wide chunks) ----------
// grid (65, 2, 2): chunk c (c==64 => the 16 new positions), group ng, row-half rh.
// Block: 32 q-rows x 128 dims vs 64 positions. Scores staged in LDS pls[32][68]:
// QK butterfly leaves full score in all 8 row-lanes -> all write same value (benign);
// softmax is computed redundantly per-lane from LDS (no shuffles, no predicated regs).
// part layout: [2][65][64][132]: acc in [0..127], m at [128], l at [129].
__global__ __launch_bounds__(256) void k_attn(const float* __restrict__ qkv,
                                              const float* __restrict__ kc,  // [2][4096][128]
                                              const float* __restrict__ vc,  // [2][128][4096]
                                              const float* __restrict__ cosp,
                                              const float* __restrict__ sinp,
                                              const float* __restrict__ mask, // [16][4112]
                                              const float* __restrict__ qnw,
                                              const float* __restrict__ knw,
                                              float* __restrict__ part,
                                              float* __restrict__ kout,   // [2][16][128]
                                              float* __restrict__ vout)   // [2][128][16]
{
    __shared__ __align__(16) float qs[32 * 132];
    __shared__ __align__(16) float kvb[64 * 132];
    __shared__ float pls[32 * 68];
    const int tid = threadIdx.x;
    const int c = blockIdx.x;
    const int ng = blockIdx.y;
    const int rh = blockIdx.z;
    const bool newc = (c == 64);

    // --- Q build: 32 rows for this half; scrambled gather + rmsnorm + rope
    {
        int rl = tid >> 3, c8 = tid & 7;
        int r = rh * 32 + rl;
        int tsrc = r >> 2, g = r & 3;
        const float* src = qkv + tsrc * OQKV + ng * 768 + g * 128;
        float ss = 0.f;
#pragma unroll
        for (int j = 0; j < 16; j++) { float v = src[c8 * 16 + j]; ss += v * v; }
        ss = r8(ss);
        float inv = rsqrtf(ss * (1.f / 128.f) + EPSF);
        int pos = r & 15;
        const float* cp = cosp + pos * 128;
        const float* sp = sinp + pos * 128;
#pragma unroll
        for (int j = 0; j < 16; j++) {
            int d = c8 * 16 + j;
            float xn = src[d] * inv * (1.f + qnw[d]);
            float out;
            if (d < 64) { float pr = src[d + 64] * inv * (1.f + qnw[d + 64]); out = xn * cp[d] - pr * sp[d]; }
            else        { float pr = src[d - 64] * inv * (1.f + qnw[d - 64]); out = xn * cp[d] + pr * sp[d]; }
            qs[rl * 132 + d] = out;
        }
    }
    // --- K stage
    if (!newc) {
        int rowk = tid >> 2, q4 = tid & 3;
        const float4* k4 = reinterpret_cast<const float4*>(kc + (size_t)(ng * SCCH + c * 64 + rowk) * 128);
#pragma unroll
        for (int k = 0; k < 8; k++) {
            float4 v = k4[q4 * 8 + k];
            *reinterpret_cast<float4*>(&kvb[rowk * 132 + 4 * (q4 * 8 + k)]) = v;
        }
    } else {
        int t = tid >> 4, c16 = tid & 15;
        const float* src = qkv + t * OQKV + ng * 768 + 4 * 128;
        float ss = 0.f;
#pragma unroll
        for (int j = 0; j < 8; j++) { float v = src[c16 * 8 + j]; ss += v * v; }
        ss = r16(ss);
        float inv = rsqrtf(ss * (1.f / 128.f) + EPSF);
        const float* cp = cosp + t * 128;
        const float* sp = sinp + t * 128;
#pragma unroll
        for (int j = 0; j < 8; j++) {
            int d = c16 * 8 + j;
            float xn = src[d] * inv * (1.f + knw[d]);
            float out;
            if (d < 64) { float pr = src[d + 64] * inv * (1.f + knw[d + 64]); out = xn * cp[d] - pr * sp[d]; }
            else        { float pr = src[d - 64] * inv * (1.f + knw[d - 64]); out = xn * cp[d] + pr * sp[d]; }
            kvb[t * 132 + d] = out;
            if (rh == 0) kout[(ng * TT + t) * 128 + d] = out;
        }
        for (int i = tid; i < 48 * 132; i += 256) kvb[16 * 132 + i] = 0.f;
    }
    __syncthreads();
    // --- scores -> pls (all 8 row-lanes hold the full dot after butterfly)
    const int rl = tid >> 3;
    const int dq = tid & 7;
    const int r = rh * 32 + rl;
    const int pos = r & 15;
    float4 qreg[4];
    {
        const float4* q4 = reinterpret_cast<const float4*>(qs + rl * 132);
#pragma unroll
        for (int mq = 0; mq < 4; mq++) qreg[mq] = q4[dq + 8 * mq];
    }
    const int cnt = newc ? TT : 64;
    const float* mrow = mask + pos * STOT + c * 64;
    float* prow = pls + rl * 68;
#pragma unroll
    for (int i = 0; i < 64; i++) {
        const float4* k4 = reinterpret_cast<const float4*>(kvb + i * 132);
        float p = d4(qreg[0], k4[dq]) + d4(qreg[1], k4[dq + 8])
                + d4(qreg[2], k4[dq + 16]) + d4(qreg[3], k4[dq + 24]);
        p += __shfl_xor(p, 1); p += __shfl_xor(p, 2); p += __shfl_xor(p, 4);
        if (i < cnt) {
            p *= SCALEQ;
            p = 50.f * tanhf(p * 0.02f);
            p += mrow[i];
        } else {
            p = -1e30f;
        }
        prow[i] = p;   // 8 lanes, same addr, same value
    }
    // --- softmax: redundant per-lane over the LDS row (wave-local, in-order)
    float m = -1e30f;
#pragma unroll
    for (int i = 0; i < 64; i++) m = fmaxf(m, prow[i]);
    float lsum = 0.f;
#pragma unroll
    for (int i = 0; i < 64; i++) lsum += __expf(prow[i] - m);
    // write exp back (each lane owns slots i = 8j+dq -> private, no race)
#pragma unroll
    for (int j = 0; j < 8; j++) {
        int i = 8 * j + dq;
        prow[i] = __expf(prow[i] - m);
    }
    __syncthreads();
    // --- V stage (reuse kvb) -> layout [pos][dim]
    if (!newc) {
        int d = tid >> 1, half = tid & 1;
        const float4* v4 = reinterpret_cast<const float4*>(vc + (size_t)(ng * 128 + d) * SCCH + c * 64);
#pragma unroll
        for (int k = 0; k < 8; k++) {
            float4 v = v4[half * 8 + k];
            int sl = half * 32 + 4 * k;
            kvb[(sl + 0) * 132 + d] = v.x;
            kvb[(sl + 1) * 132 + d] = v.y;
            kvb[(sl + 2) * 132 + d] = v.z;
            kvb[(sl + 3) * 132 + d] = v.w;
        }
    } else {
        int t = tid >> 4, c16 = tid & 15;
        const float* src = qkv + t * OQKV + ng * 768 + 5 * 128;
#pragma unroll
        for (int j = 0; j < 8; j++) {
            int d = c16 * 8 + j;
            float v = src[d];
            kvb[t * 132 + d] = v;
            if (rh == 0) vout[(ng * 128 + d) * TT + t] = v;
        }
        // rows 16..63 still zero from K stage (their probs are 0 anyway)
    }
    __syncthreads();
    // --- PV accumulate (16 dims per lane); p via LDS broadcast
    float4 accv[4];
#pragma unroll
    for (int m2 = 0; m2 < 4; m2++) accv[m2] = make_float4(0.f, 0.f, 0.f, 0.f);
#pragma unroll
    for (int i = 0; i < 64; i++) {
        float p = prow[i];
        const float4* v4 = reinterpret_cast<const float4*>(kvb + i * 132);
        accv[0] = fma4(p, v4[dq], accv[0]);
        accv[1] = fma4(p, v4[dq + 8], accv[1]);
        accv[2] = fma4(p, v4[dq + 16], accv[2]);
        accv[3] = fma4(p, v4[dq + 24], accv[3]);
    }
    float* pb = part + (size_t)((ng * 65 + c) * 64 + r) * 132;
    if (dq == 0) { pb[128] = m; pb[129] = lsum; }
    float4* pb4 = reinterpret_cast<float4*>(pb);
    pb4[dq] = accv[0]; pb4[dq + 8] = accv[1]; pb4[dq + 16] = accv[2]; pb4[dq + 24] = accv[3];
}

// ---------- K3: combine partials -> attn [t][h*128+d] ----------
__global__ __launch_bounds__(128) void k_combine(const float* __restrict__ part,
                                                 float* __restrict__ attn) {
    int blk = blockIdx.x;
    int ng = blk >> 6, r = blk & 63;
    int d = threadIdx.x;
    const float* pb = part + (size_t)(ng * 65 * 64 + r) * 132;
    float M = -1e30f;
    for (int cc = 0; cc < 65; cc++) M = fmaxf(M, pb[(size_t)cc * 64 * 132 + 128]);
    float Lsum = 0.f, A = 0.f;
    for (int cc = 0; cc < 65; cc++) {
        const float* p = pb + (size_t)cc * 64 * 132;
        float w = __expf(p[128] - M);
        Lsum = fmaf(p[129], w, Lsum);
        A = fmaf(p[d], w, A);
    }
    int h = ng * 4 + (r >> 4), pos = r & 15;
    attn[pos * 1024 + h * 128 + d] = A / Lsum;
}

// ---------- K4: out projection (reads attn straight from L2; no LDS) ----------
__global__ __launch_bounds__(256) void k_outproj(const float* __restrict__ W, // [768][1024]
                                                 const float* __restrict__ attn,
                                                 float* __restrict__ y) {
    int tid = threadIdx.x;
    int wv = tid >> 6, lane = tid & 63;
#pragma unroll
    for (int rr = 0; rr < 2; ++rr) {
        int o = blockIdx.x * 8 + rr * 4 + wv;
        float acc[TT];
        gemv_row<256>(reinterpret_cast<const float4*>(W + (size_t)o * 1024), attn, lane, acc);
        if (lane < TT) y[lane * DD + o] = acc[lane];
    }
}

// ---------- K5: post-attn residual+norm, pre-ff norm, gate/up GEMV + GELU*up ----------
__global__ __launch_bounds__(256) void k_gateup(const float* __restrict__ hA,
                                                const float* __restrict__ y,
                                                const float* __restrict__ postw,
                                                const float* __restrict__ pfn,
                                                const float* __restrict__ gw,
                                                const float* __restrict__ uw,
                                                float* __restrict__ act,
                                                float* __restrict__ hB) {
    __shared__ __align__(16) float xs[TT * DD];
    int tid = threadIdx.x;
    int row = tid >> 4, c16 = tid & 15;
    float4* xr = reinterpret_cast<float4*>(xs) + row * 192;
    const float4* y4 = reinterpret_cast<const float4*>(y) + row * 192;
    float ss = 0.f;
#pragma unroll
    for (int k = 0; k < 12; k++) { int i = c16 + 16 * k; float4 v = y4[i]; xr[i] = v; ss += d4(v, v); }
    ss = r16(ss);
    float inv = rsqrtf(ss * (1.f / 768.f) + EPSF);
    const float4* ha4 = reinterpret_cast<const float4*>(hA) + row * 192;
    const float4* pw4 = reinterpret_cast<const float4*>(postw);
    float4* hB4 = reinterpret_cast<float4*>(hB) + row * 192;
    float ss2 = 0.f;
#pragma unroll
    for (int k = 0; k < 12; k++) {
        int i = c16 + 16 * k;
        float4 v = f4res(ha4[i], xr[i], inv, pw4[i]);
        xr[i] = v; ss2 += d4(v, v);
        if (blockIdx.x == 0) hB4[i] = v;
    }
    ss2 = r16(ss2);
    float inv2 = rsqrtf(ss2 * (1.f / 768.f) + EPSF);
    const float4* pf4 = reinterpret_cast<const float4*>(pfn);
#pragma unroll
    for (int k = 0; k < 12; k++) { int i = c16 + 16 * k; xr[i] = f4nrm(xr[i], inv2, pf4[i]); }
    __syncthreads();
    int wv = tid >> 6, lane = tid & 63;
#pragma unroll
    for (int rr = 0; rr < 2; ++rr) {
        int f = blockIdx.x * 8 + rr * 4 + wv;
        float ag[TT], au[TT];
        gemv_row<192>(reinterpret_cast<const float4*>(gw + (size_t)f * DD), xs, lane, ag);
        gemv_row<192>(reinterpret_cast<const float4*>(uw + (size_t)f * DD), xs, lane, au);
        if (lane < TT) {
            float g = ag[lane], u = au[lane];
            float inner = 0.7978845608028654f * fmaf(0.044715f * g, g * g, g);
            float gel = 0.5f * g * (1.f + tanhf(inner));
            act[lane * FFF + f] = gel * u;
        }
    }
}

// ---------- K6: down GEMV in f-quarters -> ff partials [4][16][768] ----------
__global__ __launch_bounds__(256) void k_down(const float* __restrict__ W, // [768][3072]
                                              const float* __restrict__ act,
                                              float* __restrict__ ffp) {
    __shared__ __align__(16) float xs[TT * DD];
    int tid = threadIdx.x;
    int fq = blockIdx.x & 3, dc = blockIdx.x >> 2;
    {
        const float4* a4 = reinterpret_cast<const float4*>(act);
        float4* s4 = reinterpret_cast<float4*>(xs);
#pragma unroll
        for (int k = 0; k < 12; k++) {
            int i = tid + 256 * k;
            int t = i / 192, cq = i - t * 192;
            s4[i] = a4[t * 768 + fq * 192 + cq];
        }
    }
    __syncthreads();
    int wv = tid >> 6, lane = tid & 63;
#pragma unroll
    for (int rr = 0; rr < 2; ++rr) {
        int o = dc * 8 + rr * 4 + wv;
        float acc[TT];
        gemv_row<192>(reinterpret_cast<const float4*>(W + (size_t)o * FFF + fq * 768), xs, lane, acc);
        if (lane < TT) ffp[(fq * TT + lane) * DD + o] = acc[lane];
    }
}

// ---------- final x ----------
__global__ void k_finalx(const float* __restrict__ hB, const float* __restrict__ ff,
                         const float* __restrict__ pofn, const float* __restrict__ fnw,
                         float* __restrict__ xfin) {
    int t = blockIdx.x, lane = threadIdx.x;
    const float4* h4 = reinterpret_cast<const float4*>(hB) + t * 192;
    const float4* f0 = reinterpret_cast<const float4*>(ff) + t * 192;
    const float4* f1 = f0 + TT * 192;
    const float4* f2 = f1 + TT * 192;
    const float4* f3 = f2 + TT * 192;
    float4 vals[3];
    float ss = 0.f;
#pragma unroll
    for (int k = 0; k < 3; k++) {
        int i = lane + 64 * k;
        float4 s = f4add4(f0[i], f1[i], f2[i], f3[i]);
        vals[k] = s; ss += d4(s, s);
    }
    ss = rwave(ss);
    float inv = rsqrtf(ss * (1.f / 768.f) + EPSF);
    const float4* po4 = reinterpret_cast<const float4*>(pofn);
    float ss2 = 0.f;
#pragma unroll
    for (int k = 0; k < 3; k++) {
        int i = lane + 64 * k;
        float4 v = f4res(h4[i], vals[k], inv, po4[i]);
        vals[k] = v; ss2 += d4(v, v);
    }
    ss2 = rwave(ss2);
    float inv2 = rsqrtf(ss2 * (1.f / 768.f) + EPSF);
    const float4* fn4 = reinterpret_cast<const float4*>(fnw);
    float4* xf4 = reinterpret_cast<float4*>(xfin) + t * 192;
#pragma unroll
    for (int k = 0; k < 3; k++) {
        int i = lane + 64 * k;
        xf4[i] = f4nrm(vals[k], inv2, fn4[i]);
    }
}

// ---------- lm_head: logits (f32) ----------
__global__ __launch_bounds__(256) void k_lmhead(const float* __restrict__ xfin,
                                                const float* __restrict__ W, // [32000][768]
                                                float* __restrict__ logits) {
    __shared__ __align__(16) float xs[TT * DD];
    int tid = threadIdx.x;
    {
        const float4* x4 = reinterpret_cast<const float4*>(xfin);
        float4* s4 = reinterpret_cast<float4*>(xs);
#pragma unroll
        for (int k = 0; k < 12; k++) s4[tid + 256 * k] = x4[tid + 256 * k];
    }
    __syncthreads();
    int wv = tid >> 6, lane = tid & 63;
#pragma unroll
    for (int rr = 0; rr < 4; ++rr) {
        int o = blockIdx.x * 16 + rr * 4 + wv;
        float acc[TT];
        gemv_row<192>(reinterpret_cast<const float4*>(W + (size_t)o * DD), xs, lane, acc);
        if (lane < TT) logits[lane * VV + o] = acc[lane];
    }
}

extern "C" void kernel_launch(void* const* d_in, const int* in_sizes, int n_in,
                              void* d_out, int out_size, void* d_ws, size_t ws_size,
                              hipStream_t stream) {
    const float* emb   = (const float*)d_in[0];
    const float* maskg = (const float*)d_in[1];
    const float* maskl = (const float*)d_in[2];
    const float* cosg  = (const float*)d_in[3];
    const float* sing  = (const float*)d_in[4];
    const float* cosl  = (const float*)d_in[5];
    const float* sinl  = (const float*)d_in[6];
    const float* kck   = (const float*)d_in[7];
    const float* kcv   = (const float*)d_in[8];
    const float* pan   = (const float*)d_in[9];
    const float* qkvw  = (const float*)d_in[10];
    const float* qnw   = (const float*)d_in[11];
    const float* knw   = (const float*)d_in[12];
    const float* outw  = (const float*)d_in[13];
    const float* postw = (const float*)d_in[14];
    const float* pfnw  = (const float*)d_in[15];
    const float* gw    = (const float*)d_in[16];
    const float* uw    = (const float*)d_in[17];
    const float* dw    = (const float*)d_in[18];
    const float* pofn  = (const float*)d_in[19];
    const float* fnw   = (const float*)d_in[20];
    const float* lmw   = (const float*)d_in[21];

    float* ws   = (float*)d_ws;
    float* hA   = ws;                 // 12288
    float* hB   = hA + 12288;         // 12288
    float* qkv  = hB + 12288;         // 24576
    float* attn = qkv + 24576;        // 16384
    float* yb   = attn + 16384;       // 12288
    float* act  = yb + 12288;         // 49152
    float* ffp  = act + 49152;        // 49152
    float* part = ffp + 49152;        // 2*65*64*132 = 1,098,240
    float* xfin = part + 1098240;     // 12288

    float* outp = (float*)d_out;
    float* outK = outp + 512000;
    float* outV = outK + 106496;

    for (int l = 0; l < NL; l++) {
        int loc = ((l + 1) % 6) == 0;
        const float* cosp = loc ? cosl : cosg;
        const float* sinp = loc ? sinl : sing;
        const float* maskp = loc ? maskl : maskg;
        k_qkv<<<192, 256, 0, stream>>>(l == 0 ? 1 : 0, hB, ffp, emb,
                                       l ? (pofn + (size_t)(l - 1) * DD) : pofn,
                                       pan + (size_t)l * DD,
                                       qkvw + (size_t)l * OQKV * DD, qkv, hA);
        k_attn<<<dim3(65, 2, 2), 256, 0, stream>>>(qkv,
                                                   kck + (size_t)l * 2 * SCCH * HDD,
                                                   kcv + (size_t)l * 2 * HDD * SCCH,
                                                   cosp, sinp, maskp,
                                                   qnw + (size_t)l * HDD, knw + (size_t)l * HDD,
                                                   part,
                                                   outK + (size_t)l * 2 * TT * HDD,
                                                   outV + (size_t)l * 2 * HDD * TT);
        k_combine<<<128, 128, 0, stream>>>(part, attn);
        k_outproj<<<96, 256, 0, stream>>>(outw + (size_t)l * DD * 1024, attn, yb);
        k_gateup<<<384, 256, 0, stream>>>(hA, yb, postw + (size_t)l * DD, pfnw + (size_t)l * DD,
                                          gw + (size_t)l * FFF * DD, uw + (size_t)l * FFF * DD,
                                          act, hB);
        k_down<<<384, 256, 0, stream>>>(dw + (size_t)l * DD * FFF, act, ffp);
    }
    k_finalx<<<16, 64, 0, stream>>>(hB, ffp, pofn + (size_t)25 * DD, fnw, xfin);
    k_lmhead<<<2000, 256, 0, stream>>>(xfin, lmw, outp);
}

// Round 7
// 3180.837 us; speedup vs baseline: 2.7831x; 2.7831x over previous
//
#include <hip/hip_runtime.h>
#include <hip/hip_bf16.h>
#include <math.h>

// ---- problem constants ----
#define NL 26
#define TT 16
#define DD 768
#define HDD 128
#define FFF 3072
#define VV 32000
#define SCCH 4096
#define STOT 4112      // SC + T
#define OQKV 1536      // NG*(G+2)*HD
#define EPSF 1e-6f
#define SCALEQ 0.08838834764831845f  // 1/sqrt(128)

// ---------- helpers ----------
__device__ __forceinline__ float d4(const float4 a, const float4 b) {
    return fmaf(a.x, b.x, fmaf(a.y, b.y, fmaf(a.z, b.z, a.w * b.w)));
}
__device__ __forceinline__ float4 fma4(float p, const float4 v, float4 a) {
    return make_float4(fmaf(p, v.x, a.x), fmaf(p, v.y, a.y),
                       fmaf(p, v.z, a.z), fmaf(p, v.w, a.w));
}
__device__ __forceinline__ float4 f4add4(float4 a, float4 b, float4 c, float4 d) {
    return make_float4((a.x + b.x) + (c.x + d.x), (a.y + b.y) + (c.y + d.y),
                       (a.z + b.z) + (c.z + d.z), (a.w + b.w) + (c.w + d.w));
}
// h + f*s*(1+w)
__device__ __forceinline__ float4 f4res(float4 h, float4 f, float s, float4 w) {
    return make_float4(fmaf(f.x * s, 1.f + w.x, h.x), fmaf(f.y * s, 1.f + w.y, h.y),
                       fmaf(f.z * s, 1.f + w.z, h.z), fmaf(f.w * s, 1.f + w.w, h.w));
}
// h*s*(1+w)
__device__ __forceinline__ float4 f4nrm(float4 h, float s, float4 w) {
    return make_float4(h.x * s * (1.f + w.x), h.y * s * (1.f + w.y),
                       h.z * s * (1.f + w.z), h.w * s * (1.f + w.w));
}
__device__ __forceinline__ float r16(float v) {
    v += __shfl_xor(v, 1); v += __shfl_xor(v, 2); v += __shfl_xor(v, 4); v += __shfl_xor(v, 8);
    return v;
}
__device__ __forceinline__ float r8(float v) {
    v += __shfl_xor(v, 1); v += __shfl_xor(v, 2); v += __shfl_xor(v, 4);
    return v;
}
__device__ __forceinline__ float rwave(float v) {
    v += __shfl_xor(v, 32); v += __shfl_xor(v, 16); v += __shfl_xor(v, 8);
    v += __shfl_xor(v, 4);  v += __shfl_xor(v, 2);  v += __shfl_xor(v, 1);
    return v;
}

// GEMV inner: one weight row (K4 float4s) vs 16 token vectors (LDS or global).
template <int K4>
__device__ __forceinline__ void gemv_row(const float4* __restrict__ w4,
                                         const float* __restrict__ xs, int lane,
                                         float* __restrict__ acc) {
#pragma unroll
    for (int t = 0; t < TT; t++) acc[t] = 0.f;
    const float4* x4 = reinterpret_cast<const float4*>(xs);
#pragma unroll
    for (int it = 0; it < K4 / 64; ++it) {
        float4 w = w4[it * 64 + lane];
#pragma unroll
        for (int t = 0; t < TT; t++) {
            float4 x = x4[t * K4 + it * 64 + lane];
            acc[t] = fmaf(w.x, x.x, fmaf(w.y, x.y, fmaf(w.z, x.z, fmaf(w.w, x.w, acc[t]))));
        }
    }
#pragma unroll
    for (int t = 0; t < TT; t++) acc[t] = rwave(acc[t]);
}

// ---------- K1: (deferred ff residual) + pre-attn rmsnorm + QKV GEMV ----------
__global__ __launch_bounds__(256) void k_qkv(const int first,
                                             const float* __restrict__ hB,
                                             const float* __restrict__ ff,   // [4][16][768]
                                             const float* __restrict__ emb,
                                             const float* __restrict__ pofn_prev,
                                             const float* __restrict__ pan,
                                             const float* __restrict__ W,    // [1536][768]
                                             float* __restrict__ qkvo,       // [16][1536]
                                             float* __restrict__ hA) {
    __shared__ __align__(16) float xs[TT * DD];
    const int tid = threadIdx.x;
    const int row = tid >> 4, c16 = tid & 15;
    float4* xr = reinterpret_cast<float4*>(xs) + row * 192;
    float4* hA4 = reinterpret_cast<float4*>(hA) + row * 192;
    if (first) {
        const float4* e4 = reinterpret_cast<const float4*>(emb) + row * 192;
        float ss = 0.f;
#pragma unroll
        for (int k = 0; k < 12; k++) { int i = c16 + 16 * k; float4 v = e4[i]; xr[i] = v; ss += d4(v, v); }
        ss = r16(ss);
        float inv = rsqrtf(ss * (1.f / 768.f) + EPSF);
        if (blockIdx.x == 0) {
#pragma unroll
            for (int k = 0; k < 12; k++) { int i = c16 + 16 * k; hA4[i] = xr[i]; }
        }
        const float4* p4 = reinterpret_cast<const float4*>(pan);
#pragma unroll
        for (int k = 0; k < 12; k++) { int i = c16 + 16 * k; xr[i] = f4nrm(xr[i], inv, p4[i]); }
    } else {
        const float4* f0 = reinterpret_cast<const float4*>(ff) + row * 192;
        const float4* f1 = f0 + TT * 192;
        const float4* f2 = f1 + TT * 192;
        const float4* f3 = f2 + TT * 192;
        float ss = 0.f;
#pragma unroll
        for (int k = 0; k < 12; k++) {
            int i = c16 + 16 * k;
            float4 v = f4add4(f0[i], f1[i], f2[i], f3[i]);
            xr[i] = v; ss += d4(v, v);
        }
        ss = r16(ss);
        float inv = rsqrtf(ss * (1.f / 768.f) + EPSF);
        const float4* hb4 = reinterpret_cast<const float4*>(hB) + row * 192;
        const float4* po4 = reinterpret_cast<const float4*>(pofn_prev);
        float ss2 = 0.f;
#pragma unroll
        for (int k = 0; k < 12; k++) {
            int i = c16 + 16 * k;
            float4 v = f4res(hb4[i], xr[i], inv, po4[i]);
            xr[i] = v; ss2 += d4(v, v);
            if (blockIdx.x == 0) hA4[i] = v;
        }
        ss2 = r16(ss2);
        float inv2 = rsqrtf(ss2 * (1.f / 768.f) + EPSF);
        const float4* p4 = reinterpret_cast<const float4*>(pan);
#pragma unroll
        for (int k = 0; k < 12; k++) { int i = c16 + 16 * k; xr[i] = f4nrm(xr[i], inv2, p4[i]); }
    }
    __syncthreads();
    const int wv = tid >> 6, lane = tid & 63;
#pragma unroll
    for (int rr = 0; rr < 2; ++rr) {
        const int o = blockIdx.x * 8 + rr * 4 + wv;
        float acc[TT];
        gemv_row<192>(reinterpret_cast<const float4*>(W + (size_t)o * DD), xs, lane, acc);
        if (lane < TT) qkvo[lane * OQKV + o] = acc[lane];
    }
}

// ---------- K2: attention partials (flash-style over 64-wide chunks) ----------
// grid (65, 2, 2): chunk c (c==64 => the 16 new positions), group ng, row-half rh.
// Lane (rl,dq) owns positions i = 8j+dq completely: full 128-d dot streamed from
// LDS (q row broadcast within row-group, K row broadcast across row-groups).
// No shuffles in hot loops; bounded unrolling to avoid register-pressure spills.
// part layout: [2][65][64][132]: acc in [0..127], m at [128], l at [129].
__global__ __launch_bounds__(256) void k_attn(const float* __restrict__ qkv,
                                              const float* __restrict__ kc,  // [2][4096][128]
                                              const float* __restrict__ vc,  // [2][128][4096]
                                              const float* __restrict__ cosp,
                                              const float* __restrict__ sinp,
                                              const float* __restrict__ mask, // [16][4112]
                                              const float* __restrict__ qnw,
                                              const float* __restrict__ knw,
                                              float* __restrict__ part,
                                              float* __restrict__ kout,   // [2][16][128]
                                              float* __restrict__ vout)   // [2][128][16]
{
    __shared__ __align__(16) float qs[32 * 132];
    __shared__ __align__(16) float kvb[64 * 132];
    __shared__ __align__(16) float pls[32 * 72];
    const int tid = threadIdx.x;
    const int c = blockIdx.x;
    const int ng = blockIdx.y;
    const int rh = blockIdx.z;
    const bool newc = (c == 64);

    // --- Q build: 32 rows for this half; scrambled gather + rmsnorm + rope
    {
        int rl = tid >> 3, c8 = tid & 7;
        int r = rh * 32 + rl;
        int tsrc = r >> 2, g = r & 3;
        const float* src = qkv + tsrc * OQKV + ng * 768 + g * 128;
        float ss = 0.f;
#pragma unroll
        for (int j = 0; j < 16; j++) { float v = src[c8 * 16 + j]; ss += v * v; }
        ss = r8(ss);
        float inv = rsqrtf(ss * (1.f / 128.f) + EPSF);
        int pos = r & 15;
        const float* cp = cosp + pos * 128;
        const float* sp = sinp + pos * 128;
#pragma unroll
        for (int j = 0; j < 16; j++) {
            int d = c8 * 16 + j;
            float xn = src[d] * inv * (1.f + qnw[d]);
            float out;
            if (d < 64) { float pr = src[d + 64] * inv * (1.f + qnw[d + 64]); out = xn * cp[d] - pr * sp[d]; }
            else        { float pr = src[d - 64] * inv * (1.f + qnw[d - 64]); out = xn * cp[d] + pr * sp[d]; }
            qs[rl * 132 + d] = out;
        }
    }
    // --- K stage
    if (!newc) {
        int rowk = tid >> 2, q4 = tid & 3;
        const float4* k4 = reinterpret_cast<const float4*>(kc + (size_t)(ng * SCCH + c * 64 + rowk) * 128);
#pragma unroll
        for (int k = 0; k < 8; k++) {
            float4 v = k4[q4 * 8 + k];
            *reinterpret_cast<float4*>(&kvb[rowk * 132 + 4 * (q4 * 8 + k)]) = v;
        }
    } else {
        int t = tid >> 4, c16 = tid & 15;
        const float* src = qkv + t * OQKV + ng * 768 + 4 * 128;
        float ss = 0.f;
#pragma unroll
        for (int j = 0; j < 8; j++) { float v = src[c16 * 8 + j]; ss += v * v; }
        ss = r16(ss);
        float inv = rsqrtf(ss * (1.f / 128.f) + EPSF);
        const float* cp = cosp + t * 128;
        const float* sp = sinp + t * 128;
#pragma unroll
        for (int j = 0; j < 8; j++) {
            int d = c16 * 8 + j;
            float xn = src[d] * inv * (1.f + knw[d]);
            float out;
            if (d < 64) { float pr = src[d + 64] * inv * (1.f + knw[d + 64]); out = xn * cp[d] - pr * sp[d]; }
            else        { float pr = src[d - 64] * inv * (1.f + knw[d - 64]); out = xn * cp[d] + pr * sp[d]; }
            kvb[t * 132 + d] = out;
            if (rh == 0) kout[(ng * TT + t) * 128 + d] = out;
        }
        for (int i = tid; i < 48 * 132; i += 256) kvb[16 * 132 + i] = 0.f;
    }
    __syncthreads();
    // --- scores: lane (rl,dq) computes full dot for positions 8j+dq
    const int rl = tid >> 3;
    const int dq = tid & 7;
    const int r = rh * 32 + rl;
    const int pos = r & 15;
    const float4* qrow = reinterpret_cast<const float4*>(qs + rl * 132);
    const int cnt = newc ? TT : 64;
    const float* mrow = mask + pos * STOT + c * 64;
    float* prow = pls + rl * 72;
#pragma unroll 2
    for (int j = 0; j < 8; j++) {
        int i = 8 * j + dq;
        const float4* krow = reinterpret_cast<const float4*>(kvb + i * 132);
        float p = 0.f;
#pragma unroll 4
        for (int w = 0; w < 32; w++) p += d4(qrow[w], krow[w]);
        if (i < cnt) {
            p *= SCALEQ;
            p = 50.f * tanhf(p * 0.02f);
            p += mrow[i];
        } else {
            p = -1e30f;
        }
        prow[i] = p;   // owner-private slot
    }
    // --- softmax: redundant per-lane over the LDS row (wave-local, in-order)
    {
        const float4* prow4 = reinterpret_cast<const float4*>(prow);
        float m = -1e30f;
#pragma unroll 4
        for (int w = 0; w < 16; w++) {
            float4 v = prow4[w];
            m = fmaxf(m, fmaxf(fmaxf(v.x, v.y), fmaxf(v.z, v.w)));
        }
        float lsum = 0.f;
#pragma unroll 4
        for (int w = 0; w < 16; w++) {
            float4 v = prow4[w];
            lsum += (__expf(v.x - m) + __expf(v.y - m)) + (__expf(v.z - m) + __expf(v.w - m));
        }
        // write exp back (each lane owns slots i = 8j+dq -> private, no race)
#pragma unroll 2
        for (int j = 0; j < 8; j++) {
            int i = 8 * j + dq;
            prow[i] = __expf(prow[i] - m);
        }
        float* pb = part + (size_t)((ng * 65 + c) * 64 + r) * 132;
        if (dq == 0) { pb[128] = m; pb[129] = lsum; }
    }
    __syncthreads();
    // --- V stage (reuse kvb) -> layout [pos][dim]
    if (!newc) {
        int d = tid >> 1, half = tid & 1;
        const float4* v4 = reinterpret_cast<const float4*>(vc + (size_t)(ng * 128 + d) * SCCH + c * 64);
#pragma unroll
        for (int k = 0; k < 8; k++) {
            float4 v = v4[half * 8 + k];
            int sl = half * 32 + 4 * k;
            kvb[(sl + 0) * 132 + d] = v.x;
            kvb[(sl + 1) * 132 + d] = v.y;
            kvb[(sl + 2) * 132 + d] = v.z;
            kvb[(sl + 3) * 132 + d] = v.w;
        }
    } else {
        int t = tid >> 4, c16 = tid & 15;
        const float* src = qkv + t * OQKV + ng * 768 + 5 * 128;
#pragma unroll
        for (int j = 0; j < 8; j++) {
            int d = c16 * 8 + j;
            float v = src[d];
            kvb[t * 132 + d] = v;
            if (rh == 0) vout[(ng * 128 + d) * TT + t] = v;
        }
        // rows 16..63 still zero from K stage (their probs are 0 anyway)
    }
    __syncthreads();
    // --- PV accumulate (16 dims per lane); p via LDS broadcast
    float4 accv[4];
#pragma unroll
    for (int m2 = 0; m2 < 4; m2++) accv[m2] = make_float4(0.f, 0.f, 0.f, 0.f);
#pragma unroll 4
    for (int i = 0; i < 64; i++) {
        float p = prow[i];
        const float4* v4 = reinterpret_cast<const float4*>(kvb + i * 132);
        accv[0] = fma4(p, v4[dq], accv[0]);
        accv[1] = fma4(p, v4[dq + 8], accv[1]);
        accv[2] = fma4(p, v4[dq + 16], accv[2]);
        accv[3] = fma4(p, v4[dq + 24], accv[3]);
    }
    float* pb = part + (size_t)((ng * 65 + c) * 64 + r) * 132;
    float4* pb4 = reinterpret_cast<float4*>(pb);
    pb4[dq] = accv[0]; pb4[dq + 8] = accv[1]; pb4[dq + 16] = accv[2]; pb4[dq + 24] = accv[3];
}

// ---------- K3: combine partials -> attn [t][h*128+d] ----------
__global__ __launch_bounds__(128) void k_combine(const float* __restrict__ part,
                                                 float* __restrict__ attn) {
    int blk = blockIdx.x;
    int ng = blk >> 6, r = blk & 63;
    int d = threadIdx.x;
    const float* pb = part + (size_t)(ng * 65 * 64 + r) * 132;
    float M = -1e30f;
    for (int cc = 0; cc < 65; cc++) M = fmaxf(M, pb[(size_t)cc * 64 * 132 + 128]);
    float Lsum = 0.f, A = 0.f;
    for (int cc = 0; cc < 65; cc++) {
        const float* p = pb + (size_t)cc * 64 * 132;
        float w = __expf(p[128] - M);
        Lsum = fmaf(p[129], w, Lsum);
        A = fmaf(p[d], w, A);
    }
    int h = ng * 4 + (r >> 4), pos = r & 15;
    attn[pos * 1024 + h * 128 + d] = A / Lsum;
}

// ---------- K4: out projection (reads attn straight from L2; no LDS) ----------
__global__ __launch_bounds__(256) void k_outproj(const float* __restrict__ W, // [768][1024]
                                                 const float* __restrict__ attn,
                                                 float* __restrict__ y) {
    int tid = threadIdx.x;
    int wv = tid >> 6, lane = tid & 63;
#pragma unroll
    for (int rr = 0; rr < 2; ++rr) {
        int o = blockIdx.x * 8 + rr * 4 + wv;
        float acc[TT];
        gemv_row<256>(reinterpret_cast<const float4*>(W + (size_t)o * 1024), attn, lane, acc);
        if (lane < TT) y[lane * DD + o] = acc[lane];
    }
}

// ---------- K5: post-attn residual+norm, pre-ff norm, gate/up GEMV + GELU*up ----------
__global__ __launch_bounds__(256) void k_gateup(const float* __restrict__ hA,
                                                const float* __restrict__ y,
                                                const float* __restrict__ postw,
                                                const float* __restrict__ pfn,
                                                const float* __restrict__ gw,
                                                const float* __restrict__ uw,
                                                float* __restrict__ act,
                                                float* __restrict__ hB) {
    __shared__ __align__(16) float xs[TT * DD];
    int tid = threadIdx.x;
    int row = tid >> 4, c16 = tid & 15;
    float4* xr = reinterpret_cast<float4*>(xs) + row * 192;
    const float4* y4 = reinterpret_cast<const float4*>(y) + row * 192;
    float ss = 0.f;
#pragma unroll
    for (int k = 0; k < 12; k++) { int i = c16 + 16 * k; float4 v = y4[i]; xr[i] = v; ss += d4(v, v); }
    ss = r16(ss);
    float inv = rsqrtf(ss * (1.f / 768.f) + EPSF);
    const float4* ha4 = reinterpret_cast<const float4*>(hA) + row * 192;
    const float4* pw4 = reinterpret_cast<const float4*>(postw);
    float4* hB4 = reinterpret_cast<float4*>(hB) + row * 192;
    float ss2 = 0.f;
#pragma unroll
    for (int k = 0; k < 12; k++) {
        int i = c16 + 16 * k;
        float4 v = f4res(ha4[i], xr[i], inv, pw4[i]);
        xr[i] = v; ss2 += d4(v, v);
        if (blockIdx.x == 0) hB4[i] = v;
    }
    ss2 = r16(ss2);
    float inv2 = rsqrtf(ss2 * (1.f / 768.f) + EPSF);
    const float4* pf4 = reinterpret_cast<const float4*>(pfn);
#pragma unroll
    for (int k = 0; k < 12; k++) { int i = c16 + 16 * k; xr[i] = f4nrm(xr[i], inv2, pf4[i]); }
    __syncthreads();
    int wv = tid >> 6, lane = tid & 63;
#pragma unroll
    for (int rr = 0; rr < 2; ++rr) {
        int f = blockIdx.x * 8 + rr * 4 + wv;
        float ag[TT], au[TT];
        gemv_row<192>(reinterpret_cast<const float4*>(gw + (size_t)f * DD), xs, lane, ag);
        gemv_row<192>(reinterpret_cast<const float4*>(uw + (size_t)f * DD), xs, lane, au);
        if (lane < TT) {
            float g = ag[lane], u = au[lane];
            float inner = 0.7978845608028654f * fmaf(0.044715f * g, g * g, g);
            float gel = 0.5f * g * (1.f + tanhf(inner));
            act[lane * FFF + f] = gel * u;
        }
    }
}

// ---------- K6: down GEMV in f-quarters -> ff partials [4][16][768] ----------
__global__ __launch_bounds__(256) void k_down(const float* __restrict__ W, // [768][3072]
                                              const float* __restrict__ act,
                                              float* __restrict__ ffp) {
    __shared__ __align__(16) float xs[TT * DD];
    int tid = threadIdx.x;
    int fq = blockIdx.x & 3, dc = blockIdx.x >> 2;
    {
        const float4* a4 = reinterpret_cast<const float4*>(act);
        float4* s4 = reinterpret_cast<float4*>(xs);
#pragma unroll
        for (int k = 0; k < 12; k++) {
            int i = tid + 256 * k;
            int t = i / 192, cq = i - t * 192;
            s4[i] = a4[t * 768 + fq * 192 + cq];
        }
    }
    __syncthreads();
    int wv = tid >> 6, lane = tid & 63;
#pragma unroll
    for (int rr = 0; rr < 2; ++rr) {
        int o = dc * 8 + rr * 4 + wv;
        float acc[TT];
        gemv_row<192>(reinterpret_cast<const float4*>(W + (size_t)o * FFF + fq * 768), xs, lane, acc);
        if (lane < TT) ffp[(fq * TT + lane) * DD + o] = acc[lane];
    }
}

// ---------- final x ----------
__global__ void k_finalx(const float* __restrict__ hB, const float* __restrict__ ff,
                         const float* __restrict__ pofn, const float* __restrict__ fnw,
                         float* __restrict__ xfin) {
    int t = blockIdx.x, lane = threadIdx.x;
    const float4* h4 = reinterpret_cast<const float4*>(hB) + t * 192;
    const float4* f0 = reinterpret_cast<const float4*>(ff) + t * 192;
    const float4* f1 = f0 + TT * 192;
    const float4* f2 = f1 + TT * 192;
    const float4* f3 = f2 + TT * 192;
    float4 vals[3];
    float ss = 0.f;
#pragma unroll
    for (int k = 0; k < 3; k++) {
        int i = lane + 64 * k;
        float4 s = f4add4(f0[i], f1[i], f2[i], f3[i]);
        vals[k] = s; ss += d4(s, s);
    }
    ss = rwave(ss);
    float inv = rsqrtf(ss * (1.f / 768.f) + EPSF);
    const float4* po4 = reinterpret_cast<const float4*>(pofn);
    float ss2 = 0.f;
#pragma unroll
    for (int k = 0; k < 3; k++) {
        int i = lane + 64 * k;
        float4 v = f4res(h4[i], vals[k], inv, po4[i]);
        vals[k] = v; ss2 += d4(v, v);
    }
    ss2 = rwave(ss2);
    float inv2 = rsqrtf(ss2 * (1.f / 768.f) + EPSF);
    const float4* fn4 = reinterpret_cast<const float4*>(fnw);
    float4* xf4 = reinterpret_cast<float4*>(xfin) + t * 192;
#pragma unroll
    for (int k = 0; k < 3; k++) {
        int i = lane + 64 * k;
        xf4[i] = f4nrm(vals[k], inv2, fn4[i]);
    }
}

// ---------- lm_head: logits (f32) ----------
__global__ __launch_bounds__(256) void k_lmhead(const float* __restrict__ xfin,
                                                const float* __restrict__ W, // [32000][768]
                                                float* __restrict__ logits) {
    __shared__ __align__(16) float xs[TT * DD];
    int tid = threadIdx.x;
    {
        const float4* x4 = reinterpret_cast<const float4*>(xfin);
        float4* s4 = reinterpret_cast<float4*>(xs);
#pragma unroll
        for (int k = 0; k < 12; k++) s4[tid + 256 * k] = x4[tid + 256 * k];
    }
    __syncthreads();
    int wv = tid >> 6, lane = tid & 63;
#pragma unroll
    for (int rr = 0; rr < 4; ++rr) {
        int o = blockIdx.x * 16 + rr * 4 + wv;
        float acc[TT];
        gemv_row<192>(reinterpret_cast<const float4*>(W + (size_t)o * DD), xs, lane, acc);
        if (lane < TT) logits[lane * VV + o] = acc[lane];
    }
}

extern "C" void kernel_launch(void* const* d_in, const int* in_sizes, int n_in,
                              void* d_out, int out_size, void* d_ws, size_t ws_size,
                              hipStream_t stream) {
    const float* emb   = (const float*)d_in[0];
    const float* maskg = (const float*)d_in[1];
    const float* maskl = (const float*)d_in[2];
    const float* cosg  = (const float*)d_in[3];
    const float* sing  = (const float*)d_in[4];
    const float* cosl  = (const float*)d_in[5];
    const float* sinl  = (const float*)d_in[6];
    const float* kck   = (const float*)d_in[7];
    const float* kcv   = (const float*)d_in[8];
    const float* pan   = (const float*)d_in[9];
    const float* qkvw  = (const float*)d_in[10];
    const float* qnw   = (const float*)d_in[11];
    const float* knw   = (const float*)d_in[12];
    const float* outw  = (const float*)d_in[13];
    const float* postw = (const float*)d_in[14];
    const float* pfnw  = (const float*)d_in[15];
    const float* gw    = (const float*)d_in[16];
    const float* uw    = (const float*)d_in[17];
    const float* dw    = (const float*)d_in[18];
    const float* pofn  = (const float*)d_in[19];
    const float* fnw   = (const float*)d_in[20];
    const float* lmw   = (const float*)d_in[21];

    float* ws   = (float*)d_ws;
    float* hA   = ws;                 // 12288
    float* hB   = hA + 12288;         // 12288
    float* qkv  = hB + 12288;         // 24576
    float* attn = qkv + 24576;        // 16384
    float* yb   = attn + 16384;       // 12288
    float* act  = yb + 12288;         // 49152
    float* ffp  = act + 49152;        // 49152
    float* part = ffp + 49152;        // 2*65*64*132 = 1,098,240
    float* xfin = part + 1098240;     // 12288

    float* outp = (float*)d_out;
    float* outK = outp + 512000;
    float* outV = outK + 106496;

    for (int l = 0; l < NL; l++) {
        int loc = ((l + 1) % 6) == 0;
        const float* cosp = loc ? cosl : cosg;
        const float* sinp = loc ? sinl : sing;
        const float* maskp = loc ? maskl : maskg;
        k_qkv<<<192, 256, 0, stream>>>(l == 0 ? 1 : 0, hB, ffp, emb,
                                       l ? (pofn + (size_t)(l - 1) * DD) : pofn,
                                       pan + (size_t)l * DD,
                                       qkvw + (size_t)l * OQKV * DD, qkv, hA);
        k_attn<<<dim3(65, 2, 2), 256, 0, stream>>>(qkv,
                                                   kck + (size_t)l * 2 * SCCH * HDD,
                                                   kcv + (size_t)l * 2 * HDD * SCCH,
                                                   cosp, sinp, maskp,
                                                   qnw + (size_t)l * HDD, knw + (size_t)l * HDD,
                                                   part,
                                                   outK + (size_t)l * 2 * TT * HDD,
                                                   outV + (size_t)l * 2 * HDD * TT);
        k_combine<<<128, 128, 0, stream>>>(part, attn);
        k_outproj<<<96, 256, 0, stream>>>(outw + (size_t)l * DD * 1024, attn, yb);
        k_gateup<<<384, 256, 0, stream>>>(hA, yb, postw + (size_t)l * DD, pfnw + (size_t)l * DD,
                                          gw + (size_t)l * FFF * DD, uw + (size_t)l * FFF * DD,
                                          act, hB);
        k_down<<<384, 256, 0, stream>>>(dw + (size_t)l * DD * FFF, act, ffp);
    }
    k_finalx<<<16, 64, 0, stream>>>(hB, ffp, pofn + (size_t)25 * DD, fnw, xfin);
    k_lmhead<<<2000, 256, 0, stream>>>(xfin, lmw, outp);
}